// Round 2
// baseline (499.490 us; speedup 1.0000x reference)
//
#include <hip/hip_runtime.h>
#include <hip/hip_bf16.h>

#define T_LEN 2048
#define B_SZ  2048
#define H_SZ  8
#define L_SZ  4

// tanh(x) = 1 - 2/(exp(2x)+1); v_exp_f32 + v_rcp_f32, saturates correctly at +-inf
__device__ __forceinline__ float tanh_fast(float x) {
    float e = __expf(2.0f * x);
    float r = __builtin_amdgcn_rcpf(e + 1.0f);
    return __builtin_fmaf(-2.0f, r, 1.0f);
}

__global__ __launch_bounds__(64, 1)
void rnn_wavefront(const float* __restrict__ x,
                   const float* __restrict__ h0,
                   const float* __restrict__ w_ih0,
                   const float* __restrict__ w_ih,
                   const float* __restrict__ w_hh,
                   const float* __restrict__ b_ih,
                   const float* __restrict__ b_hh,
                   const float* __restrict__ w_lin,
                   const float* __restrict__ b_lin,
                   float* __restrict__ out)
{
    // x for batch element B-1, staged to LDS (pad tail so ticks k>=T read zeros)
    __shared__ __align__(16) float xs[T_LEN + 8];
    // double-buffered pipeline state: 4 layers x 8 units; lanes 32-63 keep a
    // dead mirror in [32..63] so all 64 lanes run the loop uniformly.
    __shared__ __align__(16) float st[2][64];

    const int lane = threadIdx.x;

    for (int i = lane; i < T_LEN; i += 64)
        xs[i] = x[(size_t)i * B_SZ + (B_SZ - 1)];
    if (lane < 8) xs[T_LEN + lane] = 0.0f;

    const int l  = (lane >> 3) & 3;   // layer of this lane (lanes 32-63 mirror 0-31)
    const int h  = lane & 7;          // hidden unit
    const int lp = (l == 0) ? 0 : (l - 1);

    // per-lane weights (fp32)
    float whh[H_SZ], wih[H_SZ];
    #pragma unroll
    for (int j = 0; j < H_SZ; ++j)
        whh[j] = w_hh[(l * H_SZ + h) * H_SZ + j];
    #pragma unroll
    for (int j = 0; j < H_SZ; ++j) {
        float v = w_ih[(lp * H_SZ + h) * H_SZ + j];  // lp>=0 always: address safe
        wih[j] = (l > 0) ? v : 0.0f;                 // layer 0 gets x-term instead
    }
    const float wx   = (l == 0) ? w_ih0[h] : 0.0f;
    const float bias = b_ih[l * H_SZ + h] + b_hh[l * H_SZ + h];
    const float wl   = w_lin[h];   // output weights (used by layer-3 lanes)
    const float bl   = b_lin[0];

    float hcur = h0[((size_t)l * B_SZ + (B_SZ - 1)) * H_SZ + h];
    st[0][lane] = hcur;
    st[1][lane] = hcur;
    __syncthreads();

    int buf = 0;
    // tick k: layer l computes h_l(t = k - l) (live when k >= l); layer 3 emits out[k-3]
    #pragma unroll 2
    for (int k = 0; k < T_LEN + L_SZ - 1; ++k) {
        const float* own = &st[buf][l  * H_SZ];
        const float* prv = &st[buf][lp * H_SZ];

        // balanced-tree matvec: dependent-FMA depth ~5 instead of 17
        float o0 = own[0], o1 = own[1], o2 = own[2], o3 = own[3];
        float o4 = own[4], o5 = own[5], o6 = own[6], o7 = own[7];
        float p0 = prv[0], p1 = prv[1], p2 = prv[2], p3 = prv[3];
        float p4 = prv[4], p5 = prv[5], p6 = prv[6], p7 = prv[7];
        float xt = xs[k];
        float a0 = __builtin_fmaf(whh[0], o0, whh[1] * o1);
        float a1 = __builtin_fmaf(whh[2], o2, whh[3] * o3);
        float a2 = __builtin_fmaf(whh[4], o4, whh[5] * o5);
        float a3 = __builtin_fmaf(whh[6], o6, whh[7] * o7);
        float b0 = __builtin_fmaf(wih[0], p0, wih[1] * p1);
        float b1 = __builtin_fmaf(wih[2], p2, wih[3] * p3);
        float b2 = __builtin_fmaf(wih[4], p4, wih[5] * p5);
        float b3 = __builtin_fmaf(wih[6], p6, wih[7] * p7);
        float c0 = __builtin_fmaf(wx, xt, bias);
        float s0 = (a0 + a1) + (a2 + a3);
        float s1 = (b0 + b1) + (b2 + b3);
        float hn = tanh_fast((s0 + s1) + c0);

        hcur = (k >= l) ? hn : hcur;   // warm-up: layer l live from tick l
        st[buf ^ 1][lane] = hcur;
        __syncthreads();               // orders tick-k writes vs tick-k+1 reads (1 wave: cheap)
        buf ^= 1;

        if (k >= L_SZ - 1) {
            // output dot: h3 . w_lin, reduced across the 8 layer-3 lanes
            float po = hcur * wl;
            po += __shfl_xor(po, 1);
            po += __shfl_xor(po, 2);
            po += __shfl_xor(po, 4);
            if (lane == 24) out[k - (L_SZ - 1)] = po + bl;
        }
    }
}

extern "C" void kernel_launch(void* const* d_in, const int* in_sizes, int n_in,
                              void* d_out, int out_size, void* d_ws, size_t ws_size,
                              hipStream_t stream) {
    const float* x     = (const float*)d_in[0];
    const float* h0    = (const float*)d_in[1];
    const float* w_ih0 = (const float*)d_in[2];
    const float* w_ih  = (const float*)d_in[3];
    const float* w_hh  = (const float*)d_in[4];
    const float* b_ih  = (const float*)d_in[5];
    const float* b_hh  = (const float*)d_in[6];
    const float* w_lin = (const float*)d_in[7];
    const float* b_lin = (const float*)d_in[8];
    float* out = (float*)d_out;

    rnn_wavefront<<<dim3(1), dim3(64), 0, stream>>>(
        x, h0, w_ih0, w_ih, w_hh, b_ih, b_hh, w_lin, b_lin, out);
}